// Round 1
// baseline (38669.550 us; speedup 1.0000x reference)
//
#include <hip/hip_runtime.h>
#include <hip/hip_bf16.h>
#include <stdint.h>

// Persistent-LSTM design:
//  - 256 WGs x 128 threads (2 waves), 1 WG/CU (100 KB dynamic LDS).
//  - 8 clusters of 8 batch rows. Slot A serves clusters 0-3, slot B clusters 4-7:
//    each WG time-multiplexes two independent recurrence streams so the
//    inter-WG h-exchange latency of one stream hides behind the other's compute.
//  - Per cluster, 64 WGs partition the 2048 gate columns (8 u-cols each).
//  - Weights (W 256x2048, R 512x2048) pre-staged once into LDS as bf16 in
//    MFMA B-fragment order -> one ds_read_b128 per fragment, conflict-free.
//  - Per step: A-fragments built from global x/h (fp32 -> v_cvt_pk_bf16_f32),
//    24 K-tiles of mfma_f32_16x16x32_bf16 (K=768 = 256 x + 512 h),
//    K split across the 2 waves, reduced through a small LDS zbuf.
//  - Gate math, cell state c, and h stay fp32. h exchanged via parity
//    double-buffered global buffer + per-WG monotonic flags (device scope).

#define Bb   64
#define Tt   1024
#define Ff   256
#define Uu   512
#define G4U  2048
#define KTOT 768
#define NKT  24
#define NWG  256
#define NTHR 128

#define WFRAG_ELEMS (2 * 2 * NKT * 64 * 8)          // 49152 ushorts = 96 KB
#define WFRAG_BYTES (WFRAG_ELEMS * 2)
#define ZBUF_BYTES  (2 * 2 * 16 * 16 * 4)           // 4 KB
#define SMEM_BYTES  (WFRAG_BYTES + ZBUF_BYTES)      // 102400

typedef short  bf16x8 __attribute__((ext_vector_type(8)));
typedef float  f32x4  __attribute__((ext_vector_type(4)));
typedef int    int4v  __attribute__((ext_vector_type(4)));

__device__ __forceinline__ unsigned short f2bf(float f) {
  unsigned int u = __builtin_bit_cast(unsigned int, f);
  u += 0x7fffu + ((u >> 16) & 1u);                  // RNE (inputs finite)
  return (unsigned short)(u >> 16);
}

__device__ __forceinline__ float sigf(float z) {
  return 1.f / (1.f + __expf(-z));
}

extern "C" __global__ void __launch_bounds__(NTHR, 1)
lstm_persistent(const float* __restrict__ x,
                const float* __restrict__ Wk,
                const float* __restrict__ Rk,
                const float* __restrict__ bias,
                float* __restrict__ out,
                float* __restrict__ hbuf,            // [2][B][U] fp32
                unsigned int* __restrict__ flags)    // [8][64]
{
  extern __shared__ char smem[];
  unsigned short* wfrag = (unsigned short*)smem;                 // [2][2][24][64][8] bf16
  float*          zbuf  = (float*)(smem + WFRAG_BYTES);          // [wave][nt][16][16]

  const int bid = blockIdx.x;
  const int tid = threadIdx.x;
  const int w   = tid >> 6;       // wave 0/1
  const int l   = tid & 63;       // lane

  // slot A: cluster = bid>>6 (0..3), member = bid&63
  // slot B: cluster = 4+(bid&3),     member = bid>>2
  const int kkA = bid >> 6, mA = bid & 63;
  const int kkB = 4 + (bid & 3), mB = bid >> 2;

  // ---- one-time weight staging into MFMA-fragment order ----
  for (int i = tid; i < WFRAG_ELEMS; i += NTHR) {
    const int j    = i & 7;
    const int lane = (i >> 3) & 63;
    int rest       = i >> 9;            // ((s*2+nt)*24 + kt)
    const int kt   = rest % NKT;  rest /= NKT;
    const int nt   = rest & 1;
    const int s    = rest >> 1;
    const int k    = kt * 32 + ((lane >> 4) << 3) + j;     // 0..767
    const int n    = nt * 16 + (lane & 15);                // 0..31 within WG
    const int m    = (s == 0) ? mA : mB;
    const int zc   = (n >> 3) * Uu + m * 8 + (n & 7);      // gate*512 + u
    const float v  = (k < Ff) ? Wk[(size_t)k * G4U + zc]
                              : Rk[(size_t)(k - Ff) * G4U + zc];
    wfrag[i] = f2bf(v);
  }

  // bias preload (combine threads only) + persistent cell state
  float creg[2] = {0.f, 0.f};
  float breg[2][4];
  if (tid < 64) {
    const int uu = tid & 7;
    #pragma unroll
    for (int s = 0; s < 2; ++s) {
      const int m = (s == 0) ? mA : mB;
      #pragma unroll
      for (int g = 0; g < 4; ++g) breg[s][g] = bias[g * Uu + m * 8 + uu];
    }
  }
  __syncthreads();

  for (int t = 0; t < Tt; ++t) {
    #pragma unroll
    for (int s = 0; s < 2; ++s) {
      const int kk = (s == 0) ? kkA : kkB;
      const int mm = (s == 0) ? mA : mB;

      // ---- wait until all 64 members of this cluster published h_t ----
      if (t > 0) {
        const unsigned int* fl = flags + kk * 64;
        for (;;) {
          unsigned int v = __hip_atomic_load(&fl[l], __ATOMIC_RELAXED,
                                             __HIP_MEMORY_SCOPE_AGENT);
          if (__all(v >= (unsigned int)t)) break;
          __builtin_amdgcn_s_sleep(2);
        }
        __threadfence();   // acquire: invalidate stale cached h lines
      }

      // ---- z = [x_t ; h_t] @ [W ; R] over K=768, split across 2 waves ----
      f32x4 acc0 = {0.f, 0.f, 0.f, 0.f};
      f32x4 acc1 = {0.f, 0.f, 0.f, 0.f};
      const int row = kk * 8 + (l & 7);   // A rows 8..15 alias 0..7 (ignored)
      const float* xrow = x    + ((size_t)row * Tt + t) * Ff;
      const float* hrow = hbuf + ((size_t)(t & 1) * Bb + row) * Uu;
      const int ktbase = w * 12;
      #pragma unroll
      for (int q = 0; q < 12; ++q) {
        const int kt = ktbase + q;
        const int k0 = kt * 32 + ((l >> 4) << 3);
        const float* src = (k0 < Ff) ? (xrow + k0) : (hrow + (k0 - Ff));
        const float4 v0 = *(const float4*)(src);
        const float4 v1 = *(const float4*)(src + 4);
        int r0, r1, r2, r3;
        asm("v_cvt_pk_bf16_f32 %0, %1, %2" : "=v"(r0) : "v"(v0.x), "v"(v0.y));
        asm("v_cvt_pk_bf16_f32 %0, %1, %2" : "=v"(r1) : "v"(v0.z), "v"(v0.w));
        asm("v_cvt_pk_bf16_f32 %0, %1, %2" : "=v"(r2) : "v"(v1.x), "v"(v1.y));
        asm("v_cvt_pk_bf16_f32 %0, %1, %2" : "=v"(r3) : "v"(v1.z), "v"(v1.w));
        const int4v ai = {r0, r1, r2, r3};
        const bf16x8 a = __builtin_bit_cast(bf16x8, ai);
        const unsigned short* wp =
            wfrag + ((((s * 2 + 0) * NKT + kt) * 64 + l) << 3);
        const bf16x8 b0 = *(const bf16x8*)(wp);
        const bf16x8 b1 = *(const bf16x8*)(wp + NKT * 64 * 8);
        acc0 = __builtin_amdgcn_mfma_f32_16x16x32_bf16(a, b0, acc0, 0, 0, 0);
        acc1 = __builtin_amdgcn_mfma_f32_16x16x32_bf16(a, b1, acc1, 0, 0, 0);
      }

      // ---- dump partial z tiles; cross-wave K-reduce happens in combine ----
      {
        const int col   = l & 15;
        const int rbase = (l >> 4) * 4;
        #pragma unroll
        for (int r2 = 0; r2 < 4; ++r2) {
          zbuf[((w * 2 + 0) * 16 + rbase + r2) * 16 + col] = acc0[r2];
          zbuf[((w * 2 + 1) * 16 + rbase + r2) * 16 + col] = acc1[r2];
        }
      }
      __syncthreads();

      // ---- gate math (fp32), cell update, outputs ----
      if (tid < 64) {
        const int r  = tid >> 3;   // row within cluster (0..7)
        const int uu = tid & 7;    // u within WG slice
        float z[4];
        #pragma unroll
        for (int g = 0; g < 4; ++g) {
          const int n  = g * 8 + uu;
          const int nt = n >> 4, nc = n & 15;
          z[g] = zbuf[((0 + nt) * 16 + r) * 16 + nc]
               + zbuf[((2 + nt) * 16 + r) * 16 + nc]
               + breg[s][g];
        }
        const float ig = sigf(z[0]);
        const float fg = sigf(z[1]);
        const float og = sigf(z[3]);
        const float cc = fg * creg[s] + ig * z[2];
        creg[s] = cc;
        const float hh = og * cc;
        const int b = kk * 8 + r;
        const int u = mm * 8 + uu;
        out[((size_t)b * Tt + t) * Uu + u] = tanhf(hh);
        hbuf[((size_t)((t + 1) & 1) * Bb + b) * Uu + u] = hh;
      }
      __syncthreads();   // all h stores drained (implicit vmcnt(0)) pre-flag

      if (tid == 0) {
        __threadfence();  // release: write back L2 so other XCDs see h
        __hip_atomic_store(&flags[kk * 64 + mm], (unsigned int)(t + 1),
                           __ATOMIC_RELEASE, __HIP_MEMORY_SCOPE_AGENT);
      }
    }
  }
}

extern "C" void kernel_launch(void* const* d_in, const int* in_sizes, int n_in,
                              void* d_out, int out_size, void* d_ws, size_t ws_size,
                              hipStream_t stream) {
  const float* x    = (const float*)d_in[0];
  const float* Wk   = (const float*)d_in[1];
  const float* Rk   = (const float*)d_in[2];
  const float* bias = (const float*)d_in[3];
  float* out  = (float*)d_out;
  float* hbuf = (float*)d_ws;
  unsigned int* flags =
      (unsigned int*)((char*)d_ws + (size_t)2 * Bb * Uu * sizeof(float));

  // flags + h double-buffer must be zero at every launch (h_0 = 0, flag = 0).
  const size_t init_bytes = (size_t)2 * Bb * Uu * sizeof(float)
                          + (size_t)8 * 64 * sizeof(unsigned int);
  hipMemsetAsync(d_ws, 0, init_bytes, stream);

  (void)hipFuncSetAttribute((const void*)lstm_persistent,
                            hipFuncAttributeMaxDynamicSharedMemorySize,
                            SMEM_BYTES);

  hipLaunchKernelGGL(lstm_persistent, dim3(NWG), dim3(NTHR), SMEM_BYTES, stream,
                     x, Wk, Rk, bias, out, hbuf, flags);
}

// Round 2
// 6477.041 us; speedup vs baseline: 5.9702x; 5.9702x over previous
//
#include <hip/hip_runtime.h>
#include <hip/hip_bf16.h>
#include <stdint.h>

// Persistent-LSTM, round 1: fence-free cross-XCD h exchange.
//  - 256 WGs x 128 threads (2 waves), 1 WG/CU (100 KB dynamic LDS).
//  - 8 clusters of 8 batch rows; slot A = clusters 0-3, slot B = clusters 4-7;
//    each WG time-multiplexes two independent recurrence streams.
//  - Per cluster, 64 WGs partition the 2048 gate columns (8 u-cols each).
//  - Weights pre-staged once into LDS as bf16 in MFMA B-fragment order.
//  - h exchanged as bf16 through a parity double-buffered global buffer using
//    sc0|sc1 (coherence-point) loads/stores + per-WG monotonic flags.
//    NO threadfence / buffer_wbl2 / buffer_inv anywhere: release = vmcnt(0)
//    drain of sc1 write-through stores; acquire = cache-bypassing loads.

#define Bb   64
#define Tt   1024
#define Ff   256
#define Uu   512
#define G4U  2048
#define NKT  24
#define NWG  256
#define NTHR 128

#define WFRAG_ELEMS (2 * 2 * NKT * 64 * 8)          // 49152 ushorts = 96 KB
#define WFRAG_BYTES (WFRAG_ELEMS * 2)
#define ZBUF_BYTES  (2 * 2 * 16 * 16 * 4)           // 4 KB
#define SMEM_BYTES  (WFRAG_BYTES + ZBUF_BYTES)      // 102400

typedef short  bf16x8 __attribute__((ext_vector_type(8)));
typedef float  f32x4  __attribute__((ext_vector_type(4)));
typedef int    int4v  __attribute__((ext_vector_type(4)));

__device__ __forceinline__ unsigned short f2bf(float f) {
  unsigned int u = __builtin_bit_cast(unsigned int, f);
  u += 0x7fffu + ((u >> 16) & 1u);                  // RNE (inputs finite)
  return (unsigned short)(u >> 16);
}

__device__ __forceinline__ float sigf(float z) {
  return 1.f / (1.f + __expf(-z));
}

// Coherence-point (IF$) accesses: bypass L1 + non-coherent per-XCD L2.
__device__ __forceinline__ int4v load16_sc(const unsigned short* p) {
  int4v r;
  asm volatile("global_load_dwordx4 %0, %1, off sc0 sc1"
               : "=v"(r) : "v"(p) : "memory");
  return r;
}
__device__ __forceinline__ void store2_sc(unsigned short* p, unsigned short v) {
  asm volatile("global_store_short %0, %1, off sc0 sc1"
               :: "v"(p), "v"((unsigned int)v) : "memory");
}

extern "C" __global__ void __launch_bounds__(NTHR, 1)
lstm_persistent(const float* __restrict__ x,
                const float* __restrict__ Wk,
                const float* __restrict__ Rk,
                const float* __restrict__ bias,
                float* __restrict__ out,
                unsigned short* __restrict__ hbuf,   // [2][B][U] bf16
                unsigned int* __restrict__ flags)    // [8][64]
{
  extern __shared__ char smem[];
  unsigned short* wfrag = (unsigned short*)smem;                 // [2][2][24][64][8]
  float*          zbuf  = (float*)(smem + WFRAG_BYTES);          // [wave][nt][16][16]

  const int bid = blockIdx.x;
  const int tid = threadIdx.x;
  const int w   = tid >> 6;       // wave 0/1
  const int l   = tid & 63;       // lane

  const int kkA = bid >> 6, mA = bid & 63;           // slot A cluster/member
  const int kkB = 4 + (bid & 3), mB = bid >> 2;      // slot B cluster/member

  // ---- one-time weight staging into MFMA B-fragment order ----
  for (int i = tid; i < WFRAG_ELEMS; i += NTHR) {
    const int j    = i & 7;
    const int lane = (i >> 3) & 63;
    int rest       = i >> 9;            // ((s*2+nt)*24 + kt)
    const int kt   = rest % NKT;  rest /= NKT;
    const int nt   = rest & 1;
    const int s    = rest >> 1;
    const int k    = kt * 32 + ((lane >> 4) << 3) + j;     // 0..767
    const int n    = nt * 16 + (lane & 15);                // 0..31 within WG
    const int m    = (s == 0) ? mA : mB;
    const int zc   = (n >> 3) * Uu + m * 8 + (n & 7);      // gate*512 + u
    const float v  = (k < Ff) ? Wk[(size_t)k * G4U + zc]
                              : Rk[(size_t)(k - Ff) * G4U + zc];
    wfrag[i] = f2bf(v);
  }

  float creg[2] = {0.f, 0.f};
  float breg[2][4];
  if (tid < 64) {
    const int uu = tid & 7;
    #pragma unroll
    for (int s = 0; s < 2; ++s) {
      const int m = (s == 0) ? mA : mB;
      #pragma unroll
      for (int g = 0; g < 4; ++g) breg[s][g] = bias[g * Uu + m * 8 + uu];
    }
  }
  __syncthreads();

  for (int t = 0; t < Tt; ++t) {
    #pragma unroll
    for (int s = 0; s < 2; ++s) {
      const int kk = (s == 0) ? kkA : kkB;
      const int mm = (s == 0) ? mA : mB;

      // ---- wait until all 64 members of this cluster published h_t ----
      if (t > 0) {
        const unsigned int* fl = flags + kk * 64 + l;
        for (;;) {
          unsigned int v;
          asm volatile("global_load_dword %0, %1, off sc0 sc1\n\t"
                       "s_waitcnt vmcnt(0)"
                       : "=v"(v) : "v"(fl) : "memory");
          if (__all(v >= (unsigned int)t)) break;
          __builtin_amdgcn_s_sleep(2);
        }
      }

      // ---- issue coherent h-fragment loads (overlap with x-tile MFMAs) ----
      const int row = kk * 8 + (l & 7);   // MFMA rows 8..15 alias 0..7 (ignored)
      const unsigned short* hrow = hbuf + ((size_t)(t & 1) * Bb + row) * Uu;
      int4v hfr[8];
      #pragma unroll
      for (int q = 0; q < 8; ++q) {
        const int kt = 2 * (q + 4) + w;                 // 8..23 -> h part
        const int hk = kt * 32 - Ff + ((l >> 4) << 3);  // 0..504
        hfr[q] = load16_sc(hrow + hk);
      }

      // ---- x-part K-tiles (plain cached loads; x is read-only) ----
      f32x4 acc0 = {0.f, 0.f, 0.f, 0.f};
      f32x4 acc1 = {0.f, 0.f, 0.f, 0.f};
      const float* xrow = x + ((size_t)row * Tt + t) * Ff;
      #pragma unroll
      for (int q = 0; q < 4; ++q) {
        const int kt = 2 * q + w;                       // 0..7 -> x part
        const int k0 = kt * 32 + ((l >> 4) << 3);
        const float4 v0 = *(const float4*)(xrow + k0);
        const float4 v1 = *(const float4*)(xrow + k0 + 4);
        int r0, r1, r2, r3;
        asm("v_cvt_pk_bf16_f32 %0, %1, %2" : "=v"(r0) : "v"(v0.x), "v"(v0.y));
        asm("v_cvt_pk_bf16_f32 %0, %1, %2" : "=v"(r1) : "v"(v0.z), "v"(v0.w));
        asm("v_cvt_pk_bf16_f32 %0, %1, %2" : "=v"(r2) : "v"(v1.x), "v"(v1.y));
        asm("v_cvt_pk_bf16_f32 %0, %1, %2" : "=v"(r3) : "v"(v1.z), "v"(v1.w));
        const int4v ai = {r0, r1, r2, r3};
        const bf16x8 a = __builtin_bit_cast(bf16x8, ai);
        const unsigned short* wp =
            wfrag + ((((s * 2 + 0) * NKT + kt) * 64 + l) << 3);
        const bf16x8 b0 = *(const bf16x8*)(wp);
        const bf16x8 b1 = *(const bf16x8*)(wp + NKT * 64 * 8);
        acc0 = __builtin_amdgcn_mfma_f32_16x16x32_bf16(a, b0, acc0, 0, 0, 0);
        acc1 = __builtin_amdgcn_mfma_f32_16x16x32_bf16(a, b1, acc1, 0, 0, 0);
      }

      // ---- drain asm h loads, then h-part K-tiles ----
      asm volatile("s_waitcnt vmcnt(0)" ::: "memory");
      __builtin_amdgcn_sched_barrier(0);
      #pragma unroll
      for (int q = 0; q < 8; ++q) {
        const int kt = 2 * (q + 4) + w;
        const bf16x8 a = __builtin_bit_cast(bf16x8, hfr[q]);
        const unsigned short* wp =
            wfrag + ((((s * 2 + 0) * NKT + kt) * 64 + l) << 3);
        const bf16x8 b0 = *(const bf16x8*)(wp);
        const bf16x8 b1 = *(const bf16x8*)(wp + NKT * 64 * 8);
        acc0 = __builtin_amdgcn_mfma_f32_16x16x32_bf16(a, b0, acc0, 0, 0, 0);
        acc1 = __builtin_amdgcn_mfma_f32_16x16x32_bf16(a, b1, acc1, 0, 0, 0);
      }

      // ---- dump partial z tiles; cross-wave K-reduce in combine ----
      {
        const int col   = l & 15;
        const int rbase = (l >> 4) * 4;
        #pragma unroll
        for (int r2 = 0; r2 < 4; ++r2) {
          zbuf[((w * 2 + 0) * 16 + rbase + r2) * 16 + col] = acc0[r2];
          zbuf[((w * 2 + 1) * 16 + rbase + r2) * 16 + col] = acc1[r2];
        }
      }
      __syncthreads();

      // ---- gate math (fp32), cell update, outputs ----
      if (tid < 64) {
        const int r  = tid >> 3;   // row within cluster
        const int uu = tid & 7;    // u within WG slice
        float z[4];
        #pragma unroll
        for (int g = 0; g < 4; ++g) {
          const int n  = g * 8 + uu;
          const int nt = n >> 4, nc = n & 15;
          z[g] = zbuf[((0 + nt) * 16 + r) * 16 + nc]
               + zbuf[((2 + nt) * 16 + r) * 16 + nc]
               + breg[s][g];
        }
        const float ig = sigf(z[0]);
        const float fg = sigf(z[1]);
        const float og = sigf(z[3]);
        const float cc = fg * creg[s] + ig * z[2];
        creg[s] = cc;
        const float hh = og * cc;
        const int b = kk * 8 + r;
        const int u = mm * 8 + uu;
        out[((size_t)b * Tt + t) * Uu + u] = tanhf(hh);
        store2_sc(hbuf + ((size_t)((t + 1) & 1) * Bb + b) * Uu + u, f2bf(hh));
        // release half 1: this thread's sc1 stores are at the coherence
        // point once vmcnt retires -> no buffer_wbl2 needed.
        asm volatile("s_waitcnt vmcnt(0)" ::: "memory");
      }
      __syncthreads();   // release half 2: all 64 producers drained

      if (tid == 0) {
        unsigned int fv = (unsigned int)(t + 1);
        asm volatile("global_store_dword %0, %1, off sc0 sc1"
                     :: "v"(flags + kk * 64 + mm), "v"(fv) : "memory");
      }
    }
  }
}

extern "C" void kernel_launch(void* const* d_in, const int* in_sizes, int n_in,
                              void* d_out, int out_size, void* d_ws, size_t ws_size,
                              hipStream_t stream) {
  const float* x    = (const float*)d_in[0];
  const float* Wk   = (const float*)d_in[1];
  const float* Rk   = (const float*)d_in[2];
  const float* bias = (const float*)d_in[3];
  float* out = (float*)d_out;
  unsigned short* hbuf = (unsigned short*)d_ws;
  unsigned int* flags =
      (unsigned int*)((char*)d_ws + (size_t)2 * Bb * Uu * sizeof(unsigned short));

  // h double-buffer (h_0 = 0) + flags must be zero at every launch.
  const size_t init_bytes = (size_t)2 * Bb * Uu * sizeof(unsigned short)
                          + (size_t)8 * 64 * sizeof(unsigned int);
  hipMemsetAsync(d_ws, 0, init_bytes, stream);

  (void)hipFuncSetAttribute((const void*)lstm_persistent,
                            hipFuncAttributeMaxDynamicSharedMemorySize,
                            SMEM_BYTES);

  hipLaunchKernelGGL(lstm_persistent, dim3(NWG), dim3(NTHR), SMEM_BYTES, stream,
                     x, Wk, Rk, bias, out, hbuf, flags);
}

// Round 3
// 4796.919 us; speedup vs baseline: 8.0613x; 1.3503x over previous
//
#include <hip/hip_runtime.h>
#include <stdint.h>

// Persistent-LSTM, round 2: single-hop seq-tagged h exchange.
//  - 256 WGs x 128 threads (2 waves). WG (g = bid>>6, m = bid&63) owns
//    batch rows 16g..16g+15 and u-columns 8m..8m+7 (32 z-cols, 2 nt tiles).
//  - One recurrence stream per WG; no cross-WG barriers, no flags.
//  - h element = u32 ((t+1)<<16 | bf16(h)) in parity double buffer; the
//    consumer's coherent (sc0 sc1) load IS the synchronization: tags are
//    min-reduced and checked AFTER speculative MFMAs; retry on stale.
//    2-buffer safety: a tag-(t+2) write requires full h_{t+1}, which requires
//    every WG to have finished (and thus read) step t -> no overwrite race.
//  - Weights staged once to LDS in MFMA B-frag order (48 KB); x-part weight
//    frags preloaded to VGPRs. Waves split K-tiles by parity; partial z
//    reduced through a small LDS zbuf with 2 intra-WG barriers per step.

#define Tt   1024
#define Uu   512
#define G4U  2048
#define NWG  256
#define NTHR 128

#define WF_ELEMS (2 * 24 * 64 * 8)                 // 24576 bf16 = 48 KB
#define WF_BYTES (WF_ELEMS * 2)
#define ZB_PLANE (16 * 17)                         // padded 16x16 f32 tile
#define SMEM_BYTES (WF_BYTES + 4 * ZB_PLANE * 4)   // 48 KB + 4352 B

typedef short  bf16x8 __attribute__((ext_vector_type(8)));
typedef float  f32x4  __attribute__((ext_vector_type(4)));
typedef int    int4v  __attribute__((ext_vector_type(4)));
typedef unsigned int u32;

__device__ __forceinline__ unsigned short f2bf(float f) {
  u32 u = __builtin_bit_cast(u32, f);
  u += 0x7fffu + ((u >> 16) & 1u);                 // RNE (finite inputs)
  return (unsigned short)(u >> 16);
}
__device__ __forceinline__ u32 umin32(u32 a, u32 b) { return a < b ? a : b; }

__device__ __forceinline__ int4v load16_sc(const u32* p) {
  int4v r;
  asm volatile("global_load_dwordx4 %0, %1, off sc0 sc1"
               : "=v"(r) : "v"(p));
  return r;
}
__device__ __forceinline__ void store4_sc(u32* p, u32 v) {
  asm volatile("global_store_dword %0, %1, off sc0 sc1"
               :: "v"(p), "v"(v) : "memory");
}

__device__ __forceinline__ float sigf(float z) {
  return __builtin_amdgcn_rcpf(1.f + __expf(-z));
}
__device__ __forceinline__ float tanh_fast(float v) {
  const float e = __expf(-2.f * fabsf(v));
  const float r = (1.f - e) * __builtin_amdgcn_rcpf(1.f + e);
  return copysignf(r, v);
}

extern "C" __global__ void __launch_bounds__(NTHR, 1)
lstm_persistent(const float* __restrict__ x,
                const float* __restrict__ Wk,
                const float* __restrict__ Rk,
                const float* __restrict__ bias,
                float* __restrict__ out,
                u32* __restrict__ hbuf)            // [2][64][512] tagged u32
{
  extern __shared__ char smem[];
  unsigned short* wf   = (unsigned short*)smem;            // [nt][kt][lane][8]
  float*          zbuf = (float*)(smem + WF_BYTES);        // [w][nt][16][17]

  const int bid = blockIdx.x;
  const int tid = threadIdx.x;
  const int w   = tid >> 6;
  const int l   = tid & 63;
  const int g   = bid >> 6;        // row group: batch rows 16g..16g+15
  const int m   = bid & 63;        // u-cols 8m..8m+7

  // ---- one-time weight staging into MFMA B-fragment order ----
  for (int i = tid; i < WF_ELEMS; i += NTHR) {
    const int j    = i & 7;
    const int lane = (i >> 3) & 63;
    const int kt   = (i >> 9) % 24;
    const int nt   = (i >> 9) / 24;
    const int k    = kt * 32 + ((lane >> 4) << 3) + j;     // 0..767
    const int n    = nt * 16 + (lane & 15);                // 0..31
    const int zc   = (n >> 3) * Uu + m * 8 + (n & 7);      // gate*512 + u
    const float v  = (k < 256) ? Wk[(size_t)k * G4U + zc]
                               : Rk[(size_t)(k - 256) * G4U + zc];
    wf[i] = f2bf(v);
  }
  __syncthreads();

  // ---- preload x-part weight fragments (kt = 2q+w, q=0..3) ----
  bf16x8 wfx[4][2];
  #pragma unroll
  for (int q = 0; q < 4; ++q)
    #pragma unroll
    for (int nt = 0; nt < 2; ++nt)
      wfx[q][nt] = *(const bf16x8*)(wf + (((nt * 24) + (2 * q + w)) * 64 + l) * 8);

  // ---- combine-role constants (one (row,u) pair per thread) ----
  const int row_c = tid >> 3;                  // 0..15
  const int uu    = tid & 7;
  const int b_out = g * 16 + row_c;
  const int u_out = m * 8 + uu;
  float breg[4];
  #pragma unroll
  for (int gg = 0; gg < 4; ++gg) breg[gg] = bias[gg * Uu + u_out];
  float creg = 0.f;

  // ---- load-role constants (lane-level, MFMA A-fragment) ----
  const int b_ld = g * 16 + (l & 15);
  const int kq   = (l >> 4) * 8;

  for (int t = 0; t < Tt; ++t) {
    // ---- issue coherent tagged-h loads first (latency hides under x) ----
    const u32* hp = hbuf + ((size_t)(t & 1) * 64 + b_ld) * Uu + kq;
    int4v hf[16];
    #pragma unroll
    for (int q = 0; q < 8; ++q) {
      hf[2 * q]     = load16_sc(hp + (2 * q + w) * 32);
      hf[2 * q + 1] = load16_sc(hp + (2 * q + w) * 32 + 4);
    }

    // ---- x phase: fp32 loads + cvt + 8 MFMAs (kt = 2q+w) ----
    f32x4 aX0 = {0.f, 0.f, 0.f, 0.f};
    f32x4 aX1 = {0.f, 0.f, 0.f, 0.f};
    const float* xp = x + ((size_t)b_ld * Tt + t) * 256 + kq;
    #pragma unroll
    for (int q = 0; q < 4; ++q) {
      const int kt = 2 * q + w;
      const float4 v0 = *(const float4*)(xp + kt * 32);
      const float4 v1 = *(const float4*)(xp + kt * 32 + 4);
      int r0, r1, r2, r3;
      asm("v_cvt_pk_bf16_f32 %0, %1, %2" : "=v"(r0) : "v"(v0.x), "v"(v0.y));
      asm("v_cvt_pk_bf16_f32 %0, %1, %2" : "=v"(r1) : "v"(v0.z), "v"(v0.w));
      asm("v_cvt_pk_bf16_f32 %0, %1, %2" : "=v"(r2) : "v"(v1.x), "v"(v1.y));
      asm("v_cvt_pk_bf16_f32 %0, %1, %2" : "=v"(r3) : "v"(v1.z), "v"(v1.w));
      const int4v ai = {r0, r1, r2, r3};
      const bf16x8 a = __builtin_bit_cast(bf16x8, ai);
      aX0 = __builtin_amdgcn_mfma_f32_16x16x32_bf16(a, wfx[q][0], aX0, 0, 0, 0);
      aX1 = __builtin_amdgcn_mfma_f32_16x16x32_bf16(a, wfx[q][1], aX1, 0, 0, 0);
    }

    // ---- h phase: validate-after-speculative-MFMA retry loop ----
    f32x4 aH0, aH1;
    for (;;) {
      asm volatile("s_waitcnt vmcnt(0)" ::: "memory");
      __builtin_amdgcn_sched_barrier(0);
      // tag min-reduce (4 parallel partials), runs alongside repack/MFMA
      u32 m0 = ~0u, m1 = ~0u, m2 = ~0u, m3 = ~0u;
      #pragma unroll
      for (int q = 0; q < 16; ++q) {
        m0 = umin32(m0, (u32)hf[q][0]);
        m1 = umin32(m1, (u32)hf[q][1]);
        m2 = umin32(m2, (u32)hf[q][2]);
        m3 = umin32(m3, (u32)hf[q][3]);
      }
      const u32 mv = umin32(umin32(m0, m1), umin32(m2, m3));

      aH0 = (f32x4){0.f, 0.f, 0.f, 0.f};
      aH1 = (f32x4){0.f, 0.f, 0.f, 0.f};
      #pragma unroll
      for (int q = 0; q < 8; ++q) {
        const int kt = 8 + 2 * q + w;
        const u32 w0 = __builtin_amdgcn_perm((u32)hf[2*q][1],   (u32)hf[2*q][0],   0x05040100u);
        const u32 w1 = __builtin_amdgcn_perm((u32)hf[2*q][3],   (u32)hf[2*q][2],   0x05040100u);
        const u32 w2 = __builtin_amdgcn_perm((u32)hf[2*q+1][1], (u32)hf[2*q+1][0], 0x05040100u);
        const u32 w3 = __builtin_amdgcn_perm((u32)hf[2*q+1][3], (u32)hf[2*q+1][2], 0x05040100u);
        const int4v ai = {(int)w0, (int)w1, (int)w2, (int)w3};
        const bf16x8 a = __builtin_bit_cast(bf16x8, ai);
        const bf16x8 b0 = *(const bf16x8*)(wf + ((0 * 24 + kt) * 64 + l) * 8);
        const bf16x8 b1 = *(const bf16x8*)(wf + ((1 * 24 + kt) * 64 + l) * 8);
        aH0 = __builtin_amdgcn_mfma_f32_16x16x32_bf16(a, b0, aH0, 0, 0, 0);
        aH1 = __builtin_amdgcn_mfma_f32_16x16x32_bf16(a, b1, aH1, 0, 0, 0);
      }
      if (__all((mv >> 16) == (u32)t)) break;    // all tags fresh
      __builtin_amdgcn_s_sleep(2);
      #pragma unroll
      for (int q = 0; q < 8; ++q) {              // re-issue stale loads
        hf[2 * q]     = load16_sc(hp + (2 * q + w) * 32);
        hf[2 * q + 1] = load16_sc(hp + (2 * q + w) * 32 + 4);
      }
    }

    const f32x4 z0 = aX0 + aH0;
    const f32x4 z1 = aX1 + aH1;

    // ---- cross-wave z reduce through zbuf ----
    __syncthreads();                             // WAR vs previous combine
    {
      float* zb = zbuf + ((w * 2 + 0) * 16 + (l >> 4) * 4) * 17 + (l & 15);
      #pragma unroll
      for (int r = 0; r < 4; ++r) {
        zb[r * 17]                 = z0[r];
        zb[r * 17 + 16 * 17]       = z1[r];      // nt=1 plane
      }
    }
    __syncthreads();

    // ---- gate math (fp32), cell update, outputs: 1 (row,u) per thread ----
    float z[4];
    #pragma unroll
    for (int gg = 0; gg < 4; ++gg) {
      const int n  = gg * 8 + uu;
      const int nt = n >> 4, nc = n & 15;
      z[gg] = zbuf[((0 + nt) * 16 + row_c) * 17 + nc]
            + zbuf[((2 + nt) * 16 + row_c) * 17 + nc]
            + breg[gg];
    }
    const float ig = sigf(z[0]);
    const float fg = sigf(z[1]);
    const float og = sigf(z[3]);
    const float cc = fg * creg + ig * z[2];
    creg = cc;
    const float hh = og * cc;
    out[((size_t)b_out * Tt + t) * Uu + u_out] = tanh_fast(hh);
    const u32 hw = ((u32)(t + 1) << 16) | (u32)f2bf(hh);
    store4_sc(hbuf + ((size_t)((t + 1) & 1) * 64 + b_out) * Uu + u_out, hw);
  }
}

extern "C" void kernel_launch(void* const* d_in, const int* in_sizes, int n_in,
                              void* d_out, int out_size, void* d_ws, size_t ws_size,
                              hipStream_t stream) {
  const float* x    = (const float*)d_in[0];
  const float* Wk   = (const float*)d_in[1];
  const float* Rk   = (const float*)d_in[2];
  const float* bias = (const float*)d_in[3];
  float* out = (float*)d_out;
  u32* hbuf = (u32*)d_ws;

  // zeroed hbuf == valid tag-0 h_0 = 0 for both parities.
  hipMemsetAsync(d_ws, 0, (size_t)2 * 64 * Uu * sizeof(u32), stream);

  (void)hipFuncSetAttribute((const void*)lstm_persistent,
                            hipFuncAttributeMaxDynamicSharedMemorySize,
                            SMEM_BYTES);

  hipLaunchKernelGGL(lstm_persistent, dim3(NWG), dim3(NTHR), SMEM_BYTES, stream,
                     x, Wk, Rk, bias, out, hbuf);
}